// Round 12
// baseline (482.397 us; speedup 1.0000x reference)
//
#include <hip/hip_runtime.h>
#include <math.h>

#define N_NODES 100000
#define N_EDGES 1700000
#define F0 256
#define F1 128
#define F2 64
#define NCLS 200
#define NFPAD 208
#define CAP 64

typedef short bf16x8 __attribute__((ext_vector_type(8)));
typedef float f32x4 __attribute__((ext_vector_type(4)));

__device__ __forceinline__ unsigned short f2bf(float f) {
  unsigned u = __float_as_uint(f);
  return (unsigned short)((u + 0x7FFFu + ((u >> 16) & 1u)) >> 16);
}
__device__ __forceinline__ float bflo(unsigned u) { return __uint_as_float(u << 16); }
__device__ __forceinline__ float bfhi(unsigned u) { return __uint_as_float(u & 0xFFFF0000u); }

__global__ __launch_bounds__(256) void k_dinv(const unsigned* __restrict__ cs,
                                              const unsigned* __restrict__ cnt,
                                              float* __restrict__ dsrc,
                                              float* __restrict__ ddst) {
  int i = blockIdx.x * 256 + threadIdx.x;
  if (i < N_NODES) {
    dsrc[i] = rsqrtf((float)max(cs[i], 1u));
    ddst[i] = rsqrtf((float)max(cnt[i], 1u));
  }
}

// ---------------- weight transpose+cast: Wt[n][k] = bf16(W[k][n]) ----------------
__global__ __launch_bounds__(256) void k_castw(const float* __restrict__ W,
                                               unsigned short* __restrict__ Wt,
                                               int K, int N) {
  int idx = blockIdx.x * 256 + threadIdx.x;
  if (idx < K * N) {
    int n = idx / K, k = idx % K;
    Wt[idx] = f2bf(W[(size_t)k * N + n]);
  }
}

// Wf^T zero-padded to [208][64]
__global__ __launch_bounds__(256) void k_castwf(const float* __restrict__ Wf,
                                                unsigned short* __restrict__ Wfp) {
  int idx = blockIdx.x * 256 + threadIdx.x;
  if (idx < NFPAD * F2) {
    int n = idx / F2, k = idx % F2;
    Wfp[idx] = (n < NCLS) ? f2bf(Wf[(size_t)k * NCLS + n]) : (unsigned short)0;
  }
}

// ---------------- FUSED: bucket-fill (atomic/latency-bound) + gemm1 (MFMA-bound) ----------------
__global__ __launch_bounds__(256) void k_fill_gemm1(const int* __restrict__ src,
                                                    const int* __restrict__ dst,
                                                    unsigned* __restrict__ cs,
                                                    unsigned* __restrict__ cnt,
                                                    int* __restrict__ bucket,
                                                    const float* __restrict__ X,
                                                    const unsigned short* __restrict__ Wt,
                                                    unsigned short* __restrict__ out) {
  constexpr int BM = 128;
  constexpr int BK = 64;
  constexpr int LDR = BK + 8;
  constexpr int NB_GEMM = (N_NODES + BM - 1) / BM;  // 782
  constexpr int NB_FILL = 2048;
  constexpr int TOT = NB_GEMM + NB_FILL;

  __shared__ unsigned short as[BM][LDR];
  __shared__ unsigned short bs[F1][LDR];

  const int bid = blockIdx.x;
  const int g0 = (int)(((long long)bid * NB_GEMM) / TOT);
  const int g1 = (int)(((long long)(bid + 1) * NB_GEMM) / TOT);

  if (g1 > g0) {
    const int tid = threadIdx.x;
    const int lane = tid & 63;
    const int wid = tid >> 6;
    const int wr = wid >> 1;
    const int wc = wid & 1;
    const int row0 = wr * 64;
    const int col0 = wc * 64;
    const int fq = lane >> 4;
    const int fr = lane & 15;
    const int brow0 = g0 * BM;

    f32x4 acc[4][4];
#pragma unroll
    for (int m = 0; m < 4; ++m)
#pragma unroll
      for (int n = 0; n < 4; ++n) acc[m][n] = (f32x4)(0.f);

    for (int k0 = 0; k0 < F0; k0 += BK) {
      __syncthreads();
      for (int chunk = tid; chunk < BM * (BK / 8); chunk += 256) {
        int r = chunk >> 3, c = chunk & 7;
        int gr = brow0 + r;
        float4 v0 = make_float4(0.f, 0.f, 0.f, 0.f), v1 = v0;
        if (gr < N_NODES) {
          const float* p = X + (size_t)gr * F0 + k0 + c * 8;
          v0 = *(const float4*)p;
          v1 = *(const float4*)(p + 4);
        }
        bf16x8 o;
        o[0] = (short)f2bf(v0.x); o[1] = (short)f2bf(v0.y);
        o[2] = (short)f2bf(v0.z); o[3] = (short)f2bf(v0.w);
        o[4] = (short)f2bf(v1.x); o[5] = (short)f2bf(v1.y);
        o[6] = (short)f2bf(v1.z); o[7] = (short)f2bf(v1.w);
        *(bf16x8*)&as[r][c * 8] = o;
      }
      for (int chunk = tid; chunk < F1 * (BK / 8); chunk += 256) {
        int r = chunk >> 3, c = chunk & 7;
        *(uint4*)&bs[r][c * 8] = *(const uint4*)(Wt + (size_t)r * F0 + k0 + c * 8);
      }
      __syncthreads();
#pragma unroll
      for (int ks = 0; ks < 2; ++ks) {
        bf16x8 af[4], bfv[4];
#pragma unroll
        for (int m = 0; m < 4; ++m)
          af[m] = *(const bf16x8*)&as[row0 + m * 16 + fr][ks * 32 + fq * 8];
#pragma unroll
        for (int n = 0; n < 4; ++n)
          bfv[n] = *(const bf16x8*)&bs[col0 + n * 16 + fr][ks * 32 + fq * 8];
#pragma unroll
        for (int m = 0; m < 4; ++m)
#pragma unroll
          for (int n = 0; n < 4; ++n)
            acc[m][n] = __builtin_amdgcn_mfma_f32_16x16x32_bf16(af[m], bfv[n], acc[m][n], 0, 0, 0);
      }
    }
#pragma unroll
    for (int m = 0; m < 4; ++m) {
#pragma unroll
      for (int j = 0; j < 4; ++j) {
        int grow = brow0 + row0 + m * 16 + fq * 4 + j;
        if (grow < N_NODES) {
#pragma unroll
          for (int n = 0; n < 4; ++n) {
            int col = col0 + n * 16 + fr;
            out[(size_t)grow * F1 + col] = f2bf(acc[m][n][j]);
          }
        }
      }
    }
  } else {
    const int fb = bid - g0;
    int i = fb * 256 + threadIdx.x;
    for (int e = i; e < N_EDGES; e += NB_FILL * 256) {
      int s = src[e], d = dst[e];
      unsigned p = atomicAdd(&cnt[d], 1u);
      if (p < CAP) bucket[d * CAP + p] = s;
      atomicAdd(&cs[s], 1u);
    }
  }
}

// ---------------- FUSED: gather-aggregate layer1 + gemm2 ----------------
// Phase 1: each wave gathers 32 node-aggregate rows (2-node ILP) of
//   h1f = relu((sum dsrc[s]*h1[s,:]) * ddst + b1) directly into LDS A-tile (bf16).
// Phase 2: h2 = bf16((A @ W2t) * dsrc[row]) via MFMA; B (Wt2) fully pre-staged.
__global__ __launch_bounds__(256) void k_agg_gemm2(const int* __restrict__ bucket,
                                                   const unsigned* __restrict__ cnt,
                                                   const unsigned short* __restrict__ h,
                                                   const float* __restrict__ dsrc,
                                                   const float* __restrict__ ddst,
                                                   const float* __restrict__ b1,
                                                   const unsigned short* __restrict__ wt2,
                                                   unsigned short* __restrict__ h2) {
  constexpr int BM = 128;
  constexpr int LDR = F1 + 8;  // 136
  __shared__ unsigned short as[BM][LDR];  // 34.8 KB
  __shared__ unsigned short bs[F2][LDR];  // 17.4 KB

  const int tid = threadIdx.x;
  const int lane = tid & 63;
  const int wid = tid >> 6;
  const int brow0 = blockIdx.x * BM;

  // stage B fully: wt2 is [64][128] bf16
  for (int chunk = tid; chunk < F2 * (F1 / 8); chunk += 256) {
    int r = chunk >> 4, c = chunk & 15;
    *(uint4*)&bs[r][c * 8] = *(const uint4*)(wt2 + (size_t)r * F1 + c * 8);
  }

  // ---- phase 1: gather 32 nodes per wave, processed in ILP pairs ----
  const unsigned* hp = (const unsigned*)h;  // 64 uints per h1 row
  const float2 bb = *(const float2*)(b1 + lane * 2);
  const int nbase = brow0 + wid * 32;
#pragma unroll 1
  for (int ii = 0; ii < 16; ++ii) {
    const int nA = nbase + ii * 2;
    const int nB = nA + 1;
    const int degA = (nA < N_NODES) ? (int)min(cnt[nA], (unsigned)CAP) : 0;
    const int degB = (nB < N_NODES) ? (int)min(cnt[nB], (unsigned)CAP) : 0;
    int bidxA = (lane < degA) ? bucket[(size_t)nA * CAP + lane] : 0;
    int bidxB = (lane < degB) ? bucket[(size_t)nB * CAP + lane] : 0;
    float dsvA = dsrc[bidxA];
    float dsvB = dsrc[bidxB];
    float aA0 = 0.f, aA1 = 0.f, aB0 = 0.f, aB1 = 0.f;
    int jA = 0, jB = 0;
    // joint 4+4 interleaved loop: 8 independent row loads in flight
    for (; jA + 4 <= degA && jB + 4 <= degB; jA += 4, jB += 4) {
      int sA0 = __shfl(bidxA, jA + 0), sA1 = __shfl(bidxA, jA + 1);
      int sA2 = __shfl(bidxA, jA + 2), sA3 = __shfl(bidxA, jA + 3);
      int sB0 = __shfl(bidxB, jB + 0), sB1 = __shfl(bidxB, jB + 1);
      int sB2 = __shfl(bidxB, jB + 2), sB3 = __shfl(bidxB, jB + 3);
      float dA0 = __shfl(dsvA, jA + 0), dA1 = __shfl(dsvA, jA + 1);
      float dA2 = __shfl(dsvA, jA + 2), dA3 = __shfl(dsvA, jA + 3);
      float dB0 = __shfl(dsvB, jB + 0), dB1 = __shfl(dsvB, jB + 1);
      float dB2 = __shfl(dsvB, jB + 2), dB3 = __shfl(dsvB, jB + 3);
      unsigned uA0 = hp[(size_t)sA0 * 64 + lane];
      unsigned uA1 = hp[(size_t)sA1 * 64 + lane];
      unsigned uA2 = hp[(size_t)sA2 * 64 + lane];
      unsigned uA3 = hp[(size_t)sA3 * 64 + lane];
      unsigned uB0 = hp[(size_t)sB0 * 64 + lane];
      unsigned uB1 = hp[(size_t)sB1 * 64 + lane];
      unsigned uB2 = hp[(size_t)sB2 * 64 + lane];
      unsigned uB3 = hp[(size_t)sB3 * 64 + lane];
      aA0 += dA0 * bflo(uA0) + dA1 * bflo(uA1) + dA2 * bflo(uA2) + dA3 * bflo(uA3);
      aA1 += dA0 * bfhi(uA0) + dA1 * bfhi(uA1) + dA2 * bfhi(uA2) + dA3 * bfhi(uA3);
      aB0 += dB0 * bflo(uB0) + dB1 * bflo(uB1) + dB2 * bflo(uB2) + dB3 * bflo(uB3);
      aB1 += dB0 * bfhi(uB0) + dB1 * bfhi(uB1) + dB2 * bfhi(uB2) + dB3 * bfhi(uB3);
    }
    for (; jA + 4 <= degA; jA += 4) {
      int s0 = __shfl(bidxA, jA + 0), s1 = __shfl(bidxA, jA + 1);
      int s2 = __shfl(bidxA, jA + 2), s3 = __shfl(bidxA, jA + 3);
      float d0 = __shfl(dsvA, jA + 0), d1 = __shfl(dsvA, jA + 1);
      float d2 = __shfl(dsvA, jA + 2), d3 = __shfl(dsvA, jA + 3);
      unsigned u0 = hp[(size_t)s0 * 64 + lane];
      unsigned u1 = hp[(size_t)s1 * 64 + lane];
      unsigned u2 = hp[(size_t)s2 * 64 + lane];
      unsigned u3 = hp[(size_t)s3 * 64 + lane];
      aA0 += d0 * bflo(u0) + d1 * bflo(u1) + d2 * bflo(u2) + d3 * bflo(u3);
      aA1 += d0 * bfhi(u0) + d1 * bfhi(u1) + d2 * bfhi(u2) + d3 * bfhi(u3);
    }
    for (; jA < degA; ++jA) {
      int s = __shfl(bidxA, jA);
      float d = __shfl(dsvA, jA);
      unsigned u = hp[(size_t)s * 64 + lane];
      aA0 += d * bflo(u);
      aA1 += d * bfhi(u);
    }
    for (; jB + 4 <= degB; jB += 4) {
      int s0 = __shfl(bidxB, jB + 0), s1 = __shfl(bidxB, jB + 1);
      int s2 = __shfl(bidxB, jB + 2), s3 = __shfl(bidxB, jB + 3);
      float d0 = __shfl(dsvB, jB + 0), d1 = __shfl(dsvB, jB + 1);
      float d2 = __shfl(dsvB, jB + 2), d3 = __shfl(dsvB, jB + 3);
      unsigned u0 = hp[(size_t)s0 * 64 + lane];
      unsigned u1 = hp[(size_t)s1 * 64 + lane];
      unsigned u2 = hp[(size_t)s2 * 64 + lane];
      unsigned u3 = hp[(size_t)s3 * 64 + lane];
      aB0 += d0 * bflo(u0) + d1 * bflo(u1) + d2 * bflo(u2) + d3 * bflo(u3);
      aB1 += d0 * bfhi(u0) + d1 * bfhi(u1) + d2 * bfhi(u2) + d3 * bfhi(u3);
    }
    for (; jB < degB; ++jB) {
      int s = __shfl(bidxB, jB);
      float d = __shfl(dsvB, jB);
      unsigned u = hp[(size_t)s * 64 + lane];
      aB0 += d * bflo(u);
      aB1 += d * bfhi(u);
    }
    // epilogue -> LDS A-tile
    {
      float dd = (nA < N_NODES) ? ddst[nA] : 0.f;
      float v0 = fmaxf(aA0 * dd + bb.x, 0.f);
      float v1 = fmaxf(aA1 * dd + bb.y, 0.f);
      unsigned o = (nA < N_NODES) ? ((unsigned)f2bf(v0) | ((unsigned)f2bf(v1) << 16)) : 0u;
      *(unsigned*)&as[wid * 32 + ii * 2][lane * 2] = o;
    }
    {
      float dd = (nB < N_NODES) ? ddst[nB] : 0.f;
      float v0 = fmaxf(aB0 * dd + bb.x, 0.f);
      float v1 = fmaxf(aB1 * dd + bb.y, 0.f);
      unsigned o = (nB < N_NODES) ? ((unsigned)f2bf(v0) | ((unsigned)f2bf(v1) << 16)) : 0u;
      *(unsigned*)&as[wid * 32 + ii * 2 + 1][lane * 2] = o;
    }
  }
  __syncthreads();

  // ---- phase 2: MFMA, wave w owns rows w*32..w*32+31, cols 0..63 ----
  const int fq = lane >> 4;
  const int fr = lane & 15;
  const int row0 = wid * 32;
  f32x4 acc[2][4];
#pragma unroll
  for (int m = 0; m < 2; ++m)
#pragma unroll
    for (int n = 0; n < 4; ++n) acc[m][n] = (f32x4)(0.f);

#pragma unroll
  for (int ks = 0; ks < 4; ++ks) {
    bf16x8 af[2], bfv[4];
#pragma unroll
    for (int m = 0; m < 2; ++m)
      af[m] = *(const bf16x8*)&as[row0 + m * 16 + fr][ks * 32 + fq * 8];
#pragma unroll
    for (int n = 0; n < 4; ++n)
      bfv[n] = *(const bf16x8*)&bs[n * 16 + fr][ks * 32 + fq * 8];
#pragma unroll
    for (int m = 0; m < 2; ++m)
#pragma unroll
      for (int n = 0; n < 4; ++n)
        acc[m][n] = __builtin_amdgcn_mfma_f32_16x16x32_bf16(af[m], bfv[n], acc[m][n], 0, 0, 0);
  }

#pragma unroll
  for (int m = 0; m < 2; ++m) {
#pragma unroll
    for (int j = 0; j < 4; ++j) {
      int grow = brow0 + row0 + m * 16 + fq * 4 + j;
      if (grow < N_NODES) {
        float sc = dsrc[grow];
#pragma unroll
        for (int n = 0; n < 4; ++n) {
          int col = n * 16 + fr;
          h2[(size_t)grow * F2 + col] = f2bf(acc[m][n][j] * sc);
        }
      }
    }
  }
}

// ---------------- FUSED: gather-aggregate layer2 + classifier + log_softmax ----------------
// Phase 1: each wave gathers 16 node rows of agg2 = relu((sum h2[s,:])*ddst + b2) into LDS.
// Phase 2: logits = A @ WfT + bf via MFMA; in-register softmax (shfl over 16 lanes).
__global__ __launch_bounds__(256) void k_agg_final(const int* __restrict__ bucket,
                                                   const unsigned* __restrict__ cnt,
                                                   const unsigned short* __restrict__ h,
                                                   const float* __restrict__ ddst,
                                                   const float* __restrict__ b2,
                                                   const unsigned short* __restrict__ Wfp,
                                                   const float* __restrict__ bf,
                                                   float* __restrict__ out) {
  constexpr int BM = 64;
  constexpr int NF = NFPAD / 16;  // 13
  constexpr int LDR = F2 + 8;     // 72
  __shared__ unsigned short as[BM][LDR];    // 9.2 KB
  __shared__ unsigned short bs[NFPAD][LDR]; // 30 KB

  const int tid = threadIdx.x;
  const int lane = tid & 63;
  const int wid = tid >> 6;
  const int brow0 = blockIdx.x * BM;

  // stage B (Wf^T padded [208][64])
  for (int chunk = tid; chunk < NFPAD * 8; chunk += 256) {
    int r = chunk >> 3, c = chunk & 7;
    *(uint4*)&bs[r][c * 8] = *(const uint4*)(Wfp + (size_t)r * F2 + c * 8);
  }

  // ---- phase 1: gather 16 nodes per wave (half-wave edge split) ----
  const int half = lane >> 5;
  const int fl = lane & 31;
  const unsigned* hp = (const unsigned*)h;  // 32 uints per h2 row
  const float2 bb2 = *(const float2*)(b2 + fl * 2);
#pragma unroll 1
  for (int i = 0; i < 16; ++i) {
    const int node = brow0 + wid * 16 + i;
    const int deg = (node < N_NODES) ? (int)min(cnt[node], (unsigned)CAP) : 0;
    int bidx = (lane < deg) ? bucket[(size_t)node * CAP + lane] : 0;
    float a0 = 0.f, a1 = 0.f;
    int j = half;
    for (; j + 2 < deg; j += 4) {
      int s0 = __shfl(bidx, j), s1 = __shfl(bidx, j + 2);
      unsigned u0 = hp[(size_t)s0 * 32 + fl];
      unsigned u1 = hp[(size_t)s1 * 32 + fl];
      a0 += bflo(u0) + bflo(u1);
      a1 += bfhi(u0) + bfhi(u1);
    }
    if (j < deg) {
      int s = __shfl(bidx, j);
      unsigned u = hp[(size_t)s * 32 + fl];
      a0 += bflo(u);
      a1 += bfhi(u);
    }
    a0 += __shfl_xor(a0, 32);
    a1 += __shfl_xor(a1, 32);
    if (half == 0) {
      float dd = (node < N_NODES) ? ddst[node] : 0.f;
      float v0 = fmaxf(a0 * dd + bb2.x, 0.f);
      float v1 = fmaxf(a1 * dd + bb2.y, 0.f);
      unsigned o = (node < N_NODES) ? ((unsigned)f2bf(v0) | ((unsigned)f2bf(v1) << 16)) : 0u;
      *(unsigned*)&as[wid * 16 + i][fl * 2] = o;
    }
  }
  __syncthreads();

  // ---- phase 2: MFMA + in-register log-softmax ----
  const int fq = lane >> 4;
  const int fr = lane & 15;

  f32x4 acc[NF];
#pragma unroll
  for (int n = 0; n < NF; ++n) acc[n] = (f32x4)(0.f);

#pragma unroll
  for (int ks = 0; ks < 2; ++ks) {
    bf16x8 af = *(const bf16x8*)&as[wid * 16 + fr][ks * 32 + fq * 8];
#pragma unroll
    for (int n = 0; n < NF; ++n) {
      bf16x8 bv = *(const bf16x8*)&bs[n * 16 + fr][ks * 32 + fq * 8];
      acc[n] = __builtin_amdgcn_mfma_f32_16x16x32_bf16(af, bv, acc[n], 0, 0, 0);
    }
  }

  const int nval = (fr < NCLS - (NF - 1) * 16) ? NF : NF - 1;
  float bias[NF];
#pragma unroll
  for (int n = 0; n < NF; ++n) {
    int col = n * 16 + fr;
    bias[n] = (col < NCLS) ? bf[col] : 0.f;
  }

#pragma unroll
  for (int j = 0; j < 4; ++j) {
    const int grow = brow0 + wid * 16 + fq * 4 + j;
    float v[NF];
    float m = -1e30f;
#pragma unroll
    for (int n = 0; n < NF; ++n) {
      v[n] = acc[n][j] + bias[n];
      if (n < nval) m = fmaxf(m, v[n]);
    }
#pragma unroll
    for (int o = 1; o < 16; o <<= 1) m = fmaxf(m, __shfl_xor(m, o));
    float s = 0.f;
#pragma unroll
    for (int n = 0; n < NF; ++n)
      if (n < nval) s += expf(v[n] - m);
#pragma unroll
    for (int o = 1; o < 16; o <<= 1) s += __shfl_xor(s, o);
    float ls = logf(s);
    if (grow < N_NODES) {
#pragma unroll
      for (int n = 0; n < NF; ++n)
        if (n < nval) out[(size_t)grow * NCLS + n * 16 + fr] = v[n] - m - ls;
    }
  }
}

extern "C" void kernel_launch(void* const* d_in, const int* in_sizes, int n_in,
                              void* d_out, int out_size, void* d_ws, size_t ws_size,
                              hipStream_t stream) {
  const float* x = (const float*)d_in[0];
  const int* src = (const int*)d_in[1];
  const int* dst = (const int*)d_in[2];
  const float* W1 = (const float*)d_in[3];
  const float* b1 = (const float*)d_in[4];
  const float* W2 = (const float*)d_in[5];
  const float* b2 = (const float*)d_in[6];
  const float* Wf = (const float*)d_in[7];
  const float* bf = (const float*)d_in[8];
  float* out = (float*)d_out;

  // ---- workspace layout (~66 MB), 256B-aligned blocks ----
  char* base = (char*)d_ws;
  size_t off = 0;
  auto alloc = [&](size_t bytes) -> void* {
    off = (off + 255) & ~(size_t)255;
    void* p = base + off;
    off += bytes;
    return p;
  };
  // cs and cnt as ONE contiguous block so a single memset covers both
  unsigned* cs = (unsigned*)alloc(2 * (size_t)N_NODES * 4);
  unsigned* cnt = cs + N_NODES;
  float* dsrc = (float*)alloc(N_NODES * 4);
  float* ddst = (float*)alloc(N_NODES * 4);
  int* bucket = (int*)alloc((size_t)N_NODES * CAP * 4);                   // 25.6 MB
  unsigned short* h1 = (unsigned short*)alloc((size_t)N_NODES * F1 * 2);  // 25.6 MB
  unsigned short* h2 = (unsigned short*)alloc((size_t)N_NODES * F2 * 2);  // 12.8 MB
  unsigned short* wt1 = (unsigned short*)alloc((size_t)F1 * F0 * 2);
  unsigned short* wt2 = (unsigned short*)alloc((size_t)F2 * F1 * 2);
  unsigned short* wtf = (unsigned short*)alloc((size_t)NFPAD * F2 * 2);

  hipMemsetAsync(cs, 0, 2 * (size_t)N_NODES * sizeof(unsigned), stream);

  k_castw<<<(F0 * F1 + 255) / 256, 256, 0, stream>>>(W1, wt1, F0, F1);
  k_castw<<<(F1 * F2 + 255) / 256, 256, 0, stream>>>(W2, wt2, F1, F2);
  k_castwf<<<(NFPAD * F2 + 255) / 256, 256, 0, stream>>>(Wf, wtf);

  // fused: bucket-fill + layer-1 GEMM (no cross-dependency; roles interleaved)
  constexpr int NB_GEMM = (N_NODES + 127) / 128;
  constexpr int NB_FILL = 2048;
  k_fill_gemm1<<<NB_GEMM + NB_FILL, 256, 0, stream>>>(src, dst, cs, cnt, bucket, x, wt1, h1);

  k_dinv<<<(N_NODES + 255) / 256, 256, 0, stream>>>(cs, cnt, dsrc, ddst);

  // fused: layer-1 aggregate -> layer-2 GEMM (A-tile gathered straight into LDS)
  k_agg_gemm2<<<(N_NODES + 127) / 128, 256, 0, stream>>>(bucket, cnt, h1, dsrc, ddst, b1, wt2, h2);

  // fused: layer-2 aggregate -> classifier + log_softmax
  k_agg_final<<<(N_NODES + 63) / 64, 256, 0, stream>>>(bucket, cnt, h2, ddst, b2, wtf, bf, out);
}

// Round 13
// 327.929 us; speedup vs baseline: 1.4710x; 1.4710x over previous
//
#include <hip/hip_runtime.h>
#include <math.h>

#define N_NODES 100000
#define N_EDGES 1700000
#define F0 256
#define F1 128
#define F2 64
#define NCLS 200
#define NFPAD 208
#define CAP 64

typedef short bf16x8 __attribute__((ext_vector_type(8)));
typedef float f32x4 __attribute__((ext_vector_type(4)));

__device__ __forceinline__ unsigned short f2bf(float f) {
  unsigned u = __float_as_uint(f);
  return (unsigned short)((u + 0x7FFFu + ((u >> 16) & 1u)) >> 16);
}
__device__ __forceinline__ float bflo(unsigned u) { return __uint_as_float(u << 16); }
__device__ __forceinline__ float bfhi(unsigned u) { return __uint_as_float(u & 0xFFFF0000u); }

// ---------------- merged weight transpose+cast: wt1, wt2, wtf in one launch ----------------
__global__ __launch_bounds__(256) void k_castall(const float* __restrict__ W1,
                                                 const float* __restrict__ W2,
                                                 const float* __restrict__ Wf,
                                                 unsigned short* __restrict__ wt1,
                                                 unsigned short* __restrict__ wt2,
                                                 unsigned short* __restrict__ wtf) {
  int idx = blockIdx.x * 256 + threadIdx.x;
  if (idx < F1 * F0) {                      // wt1[n][k] = bf16(W1[k][n])
    int n = idx / F0, k = idx % F0;
    wt1[idx] = f2bf(W1[(size_t)k * F1 + n]);
  } else if (idx < F1 * F0 + F2 * F1) {     // wt2[n][k] = bf16(W2[k][n])
    int t = idx - F1 * F0;
    int n = t / F1, k = t % F1;
    wt2[t] = f2bf(W2[(size_t)k * F2 + n]);
  } else if (idx < F1 * F0 + F2 * F1 + NFPAD * F2) {  // wtf zero-padded [208][64]
    int t = idx - F1 * F0 - F2 * F1;
    int n = t / F2, k = t % F2;
    wtf[t] = (n < NCLS) ? f2bf(Wf[(size_t)k * NCLS + n]) : (unsigned short)0;
  }
}

// ---------------- FUSED: bucket-fill (atomic/latency-bound) + gemm1 (MFMA-bound) ----------------
__global__ __launch_bounds__(256) void k_fill_gemm1(const int* __restrict__ src,
                                                    const int* __restrict__ dst,
                                                    unsigned* __restrict__ cs,
                                                    unsigned* __restrict__ cnt,
                                                    int* __restrict__ bucket,
                                                    const float* __restrict__ X,
                                                    const unsigned short* __restrict__ Wt,
                                                    unsigned short* __restrict__ out) {
  constexpr int BM = 128;
  constexpr int BK = 64;
  constexpr int LDR = BK + 8;
  constexpr int NB_GEMM = (N_NODES + BM - 1) / BM;  // 782
  constexpr int NB_FILL = 2048;
  constexpr int TOT = NB_GEMM + NB_FILL;

  __shared__ unsigned short as[BM][LDR];
  __shared__ unsigned short bs[F1][LDR];

  const int bid = blockIdx.x;
  const int g0 = (int)(((long long)bid * NB_GEMM) / TOT);
  const int g1 = (int)(((long long)(bid + 1) * NB_GEMM) / TOT);

  if (g1 > g0) {
    const int tid = threadIdx.x;
    const int lane = tid & 63;
    const int wid = tid >> 6;
    const int wr = wid >> 1;
    const int wc = wid & 1;
    const int row0 = wr * 64;
    const int col0 = wc * 64;
    const int fq = lane >> 4;
    const int fr = lane & 15;
    const int brow0 = g0 * BM;

    f32x4 acc[4][4];
#pragma unroll
    for (int m = 0; m < 4; ++m)
#pragma unroll
      for (int n = 0; n < 4; ++n) acc[m][n] = (f32x4)(0.f);

    for (int k0 = 0; k0 < F0; k0 += BK) {
      __syncthreads();
      for (int chunk = tid; chunk < BM * (BK / 8); chunk += 256) {
        int r = chunk >> 3, c = chunk & 7;
        int gr = brow0 + r;
        float4 v0 = make_float4(0.f, 0.f, 0.f, 0.f), v1 = v0;
        if (gr < N_NODES) {
          const float* p = X + (size_t)gr * F0 + k0 + c * 8;
          v0 = *(const float4*)p;
          v1 = *(const float4*)(p + 4);
        }
        bf16x8 o;
        o[0] = (short)f2bf(v0.x); o[1] = (short)f2bf(v0.y);
        o[2] = (short)f2bf(v0.z); o[3] = (short)f2bf(v0.w);
        o[4] = (short)f2bf(v1.x); o[5] = (short)f2bf(v1.y);
        o[6] = (short)f2bf(v1.z); o[7] = (short)f2bf(v1.w);
        *(bf16x8*)&as[r][c * 8] = o;
      }
      for (int chunk = tid; chunk < F1 * (BK / 8); chunk += 256) {
        int r = chunk >> 3, c = chunk & 7;
        *(uint4*)&bs[r][c * 8] = *(const uint4*)(Wt + (size_t)r * F0 + k0 + c * 8);
      }
      __syncthreads();
#pragma unroll
      for (int ks = 0; ks < 2; ++ks) {
        bf16x8 af[4], bfv[4];
#pragma unroll
        for (int m = 0; m < 4; ++m)
          af[m] = *(const bf16x8*)&as[row0 + m * 16 + fr][ks * 32 + fq * 8];
#pragma unroll
        for (int n = 0; n < 4; ++n)
          bfv[n] = *(const bf16x8*)&bs[col0 + n * 16 + fr][ks * 32 + fq * 8];
#pragma unroll
        for (int m = 0; m < 4; ++m)
#pragma unroll
          for (int n = 0; n < 4; ++n)
            acc[m][n] = __builtin_amdgcn_mfma_f32_16x16x32_bf16(af[m], bfv[n], acc[m][n], 0, 0, 0);
      }
    }
#pragma unroll
    for (int m = 0; m < 4; ++m) {
#pragma unroll
      for (int j = 0; j < 4; ++j) {
        int grow = brow0 + row0 + m * 16 + fq * 4 + j;
        if (grow < N_NODES) {
#pragma unroll
          for (int n = 0; n < 4; ++n) {
            int col = col0 + n * 16 + fr;
            out[(size_t)grow * F1 + col] = f2bf(acc[m][n][j]);
          }
        }
      }
    }
  } else {
    const int fb = bid - g0;
    int i = fb * 256 + threadIdx.x;
    for (int e = i; e < N_EDGES; e += NB_FILL * 256) {
      int s = src[e], d = dst[e];
      unsigned p = atomicAdd(&cnt[d], 1u);
      if (p < CAP) bucket[d * CAP + p] = s;
      atomicAdd(&cs[s], 1u);
    }
  }
}

// ---------------- gather F=128 bf16: shfl-preload; norms computed inline from cs/cnt ----------------
__global__ __launch_bounds__(256) void k_gather128(const int* __restrict__ bucket,
                                                   const unsigned* __restrict__ cs,
                                                   const unsigned* __restrict__ cnt,
                                                   const unsigned short* __restrict__ h,
                                                   const float* __restrict__ b,
                                                   unsigned short* __restrict__ out) {
  const int lane = threadIdx.x & 63;
  const int node = blockIdx.x * 4 + (threadIdx.x >> 6);
  if (node >= N_NODES) return;
  const unsigned craw = cnt[node];
  const int deg = (int)min(craw, (unsigned)CAP);
  const int* bp = bucket + (size_t)node * CAP;
  int bidx = (lane < deg) ? bp[lane] : 0;
  float dsv = rsqrtf((float)max(cs[bidx], 1u));  // dsrc inline
  const unsigned* hp = (const unsigned*)h;  // 64 uints per row
  float a0 = 0.f, a1 = 0.f;
  int j = 0;
  for (; j + 4 <= deg; j += 4) {
    int s0 = __shfl(bidx, j + 0), s1 = __shfl(bidx, j + 1);
    int s2 = __shfl(bidx, j + 2), s3 = __shfl(bidx, j + 3);
    float d0 = __shfl(dsv, j + 0), d1 = __shfl(dsv, j + 1);
    float d2 = __shfl(dsv, j + 2), d3 = __shfl(dsv, j + 3);
    unsigned u0 = hp[(size_t)s0 * 64 + lane];
    unsigned u1 = hp[(size_t)s1 * 64 + lane];
    unsigned u2 = hp[(size_t)s2 * 64 + lane];
    unsigned u3 = hp[(size_t)s3 * 64 + lane];
    a0 += d0 * bflo(u0) + d1 * bflo(u1) + d2 * bflo(u2) + d3 * bflo(u3);
    a1 += d0 * bfhi(u0) + d1 * bfhi(u1) + d2 * bfhi(u2) + d3 * bfhi(u3);
  }
  for (; j < deg; ++j) {
    int s = __shfl(bidx, j);
    float ds = __shfl(dsv, j);
    unsigned u = hp[(size_t)s * 64 + lane];
    a0 += ds * bflo(u);
    a1 += ds * bfhi(u);
  }
  float dd = rsqrtf((float)max(craw, 1u));  // ddst inline (free: cnt already loaded)
  float2 bb = *(const float2*)(b + lane * 2);
  float v0 = fmaxf(a0 * dd + bb.x, 0.f);
  float v1 = fmaxf(a1 * dd + bb.y, 0.f);
  unsigned o = (unsigned)f2bf(v0) | ((unsigned)f2bf(v1) << 16);
  ((unsigned*)out)[(size_t)node * 64 + lane] = o;
}

// ---------------- MFMA GEMM layer 2 (BM=64 for 2x grid / TLP): h2 = bf16((h1f @ W2) * dsrc) ----------------
__global__ __launch_bounds__(128) void k_gemm2(const unsigned short* __restrict__ X,
                                               const unsigned short* __restrict__ Wt,
                                               const unsigned* __restrict__ cs,
                                               unsigned short* __restrict__ out) {
  constexpr int BM = 64;
  constexpr int BK = 64;
  constexpr int LDR = BK + 8;
  __shared__ unsigned short as[BM][LDR];  // 9.2 KB
  __shared__ unsigned short bs[F2][LDR];  // 9.2 KB

  const int tid = threadIdx.x;
  const int lane = tid & 63;
  const int wid = tid >> 6;     // 2 waves; wave owns 32 rows x 64 cols
  const int row0 = wid * 32;
  const int fq = lane >> 4;
  const int fr = lane & 15;
  const int brow0 = blockIdx.x * BM;

  f32x4 acc[2][4];
#pragma unroll
  for (int m = 0; m < 2; ++m)
#pragma unroll
    for (int n = 0; n < 4; ++n) acc[m][n] = (f32x4)(0.f);

  for (int k0 = 0; k0 < F1; k0 += BK) {
    __syncthreads();
    for (int chunk = tid; chunk < BM * (BK / 8); chunk += 128) {
      int r = chunk >> 3, c = chunk & 7;
      int gr = brow0 + r;
      uint4 v = make_uint4(0u, 0u, 0u, 0u);
      if (gr < N_NODES) v = *(const uint4*)(X + (size_t)gr * F1 + k0 + c * 8);
      *(uint4*)&as[r][c * 8] = v;
    }
    for (int chunk = tid; chunk < F2 * (BK / 8); chunk += 128) {
      int r = chunk >> 3, c = chunk & 7;
      *(uint4*)&bs[r][c * 8] = *(const uint4*)(Wt + (size_t)r * F1 + k0 + c * 8);
    }
    __syncthreads();
#pragma unroll
    for (int ks = 0; ks < 2; ++ks) {
      bf16x8 af[2], bfv[4];
#pragma unroll
      for (int m = 0; m < 2; ++m)
        af[m] = *(const bf16x8*)&as[row0 + m * 16 + fr][ks * 32 + fq * 8];
#pragma unroll
      for (int n = 0; n < 4; ++n)
        bfv[n] = *(const bf16x8*)&bs[n * 16 + fr][ks * 32 + fq * 8];
#pragma unroll
      for (int m = 0; m < 2; ++m)
#pragma unroll
        for (int n = 0; n < 4; ++n)
          acc[m][n] = __builtin_amdgcn_mfma_f32_16x16x32_bf16(af[m], bfv[n], acc[m][n], 0, 0, 0);
    }
  }

#pragma unroll
  for (int m = 0; m < 2; ++m) {
#pragma unroll
    for (int j = 0; j < 4; ++j) {
      int grow = brow0 + row0 + m * 16 + fq * 4 + j;
      if (grow < N_NODES) {
        float sc = rsqrtf((float)max(cs[grow], 1u));  // dsrc inline
#pragma unroll
        for (int n = 0; n < 4; ++n) {
          int col = n * 16 + fr;
          out[(size_t)grow * F2 + col] = f2bf(acc[m][n][j] * sc);
        }
      }
    }
  }
}

// ---------------- gather F=64 bf16 -> bf16: shfl-preload; ddst inline ----------------
__global__ __launch_bounds__(256) void k_gather64(const int* __restrict__ bucket,
                                                  const unsigned* __restrict__ cnt,
                                                  const unsigned short* __restrict__ h,
                                                  const float* __restrict__ b,
                                                  unsigned short* __restrict__ out) {
  const int lane = threadIdx.x & 63;
  const int node = blockIdx.x * 4 + (threadIdx.x >> 6);
  if (node >= N_NODES) return;
  const int half = lane >> 5;
  const int fl = lane & 31;
  const unsigned craw = cnt[node];
  const int deg = (int)min(craw, (unsigned)CAP);
  const int* bp = bucket + (size_t)node * CAP;
  int bidx = (lane < deg) ? bp[lane] : 0;
  const unsigned* hp = (const unsigned*)h;  // 32 uints per row
  float a0 = 0.f, a1 = 0.f;
  int j = half;
  for (; j + 2 < deg; j += 4) {
    int s0 = __shfl(bidx, j), s1 = __shfl(bidx, j + 2);
    unsigned u0 = hp[(size_t)s0 * 32 + fl];
    unsigned u1 = hp[(size_t)s1 * 32 + fl];
    a0 += bflo(u0) + bflo(u1);
    a1 += bfhi(u0) + bfhi(u1);
  }
  if (j < deg) {
    int s = __shfl(bidx, j);
    unsigned u = hp[(size_t)s * 32 + fl];
    a0 += bflo(u);
    a1 += bfhi(u);
  }
  a0 += __shfl_xor(a0, 32);
  a1 += __shfl_xor(a1, 32);
  if (half == 0) {
    float dd = rsqrtf((float)max(craw, 1u));
    float2 bb = *(const float2*)(b + fl * 2);
    float v0 = fmaxf(a0 * dd + bb.x, 0.f);
    float v1 = fmaxf(a1 * dd + bb.y, 0.f);
    unsigned o = (unsigned)f2bf(v0) | ((unsigned)f2bf(v1) << 16);
    ((unsigned*)out)[(size_t)node * 32 + fl] = o;
  }
}

// ---------------- final (MFMA): logits = h @ Wf + bf; out = log_softmax ----------------
__global__ __launch_bounds__(256) void k_final_mfma(const unsigned short* __restrict__ h,
                                                    const unsigned short* __restrict__ Wfp,
                                                    const float* __restrict__ bf,
                                                    float* __restrict__ out) {
  constexpr int BM = 64;
  constexpr int NF = NFPAD / 16;  // 13
  constexpr int LDR = F2 + 8;     // 72
  __shared__ unsigned short as[BM][LDR];
  __shared__ unsigned short bs[NFPAD][LDR];

  const int tid = threadIdx.x;
  const int lane = tid & 63;
  const int wid = tid >> 6;
  const int fq = lane >> 4;
  const int fr = lane & 15;
  const int brow0 = blockIdx.x * BM;

  for (int chunk = tid; chunk < BM * 8; chunk += 256) {
    int r = chunk >> 3, c = chunk & 7;
    int gr = brow0 + r;
    uint4 v = make_uint4(0u, 0u, 0u, 0u);
    if (gr < N_NODES) v = *(const uint4*)(h + (size_t)gr * F2 + c * 8);
    *(uint4*)&as[r][c * 8] = v;
  }
  for (int chunk = tid; chunk < NFPAD * 8; chunk += 256) {
    int r = chunk >> 3, c = chunk & 7;
    *(uint4*)&bs[r][c * 8] = *(const uint4*)(Wfp + (size_t)r * F2 + c * 8);
  }
  __syncthreads();

  f32x4 acc[NF];
#pragma unroll
  for (int n = 0; n < NF; ++n) acc[n] = (f32x4)(0.f);

#pragma unroll
  for (int ks = 0; ks < 2; ++ks) {
    bf16x8 af = *(const bf16x8*)&as[wid * 16 + fr][ks * 32 + fq * 8];
#pragma unroll
    for (int n = 0; n < NF; ++n) {
      bf16x8 bv = *(const bf16x8*)&bs[n * 16 + fr][ks * 32 + fq * 8];
      acc[n] = __builtin_amdgcn_mfma_f32_16x16x32_bf16(af, bv, acc[n], 0, 0, 0);
    }
  }

  const int nval = (fr < NCLS - (NF - 1) * 16) ? NF : NF - 1;
  float bias[NF];
#pragma unroll
  for (int n = 0; n < NF; ++n) {
    int col = n * 16 + fr;
    bias[n] = (col < NCLS) ? bf[col] : 0.f;
  }

#pragma unroll
  for (int j = 0; j < 4; ++j) {
    const int grow = brow0 + wid * 16 + fq * 4 + j;
    float v[NF];
    float m = -1e30f;
#pragma unroll
    for (int n = 0; n < NF; ++n) {
      v[n] = acc[n][j] + bias[n];
      if (n < nval) m = fmaxf(m, v[n]);
    }
#pragma unroll
    for (int o = 1; o < 16; o <<= 1) m = fmaxf(m, __shfl_xor(m, o));
    float s = 0.f;
#pragma unroll
    for (int n = 0; n < NF; ++n)
      if (n < nval) s += expf(v[n] - m);
#pragma unroll
    for (int o = 1; o < 16; o <<= 1) s += __shfl_xor(s, o);
    float ls = logf(s);
    if (grow < N_NODES) {
#pragma unroll
      for (int n = 0; n < NF; ++n)
        if (n < nval) out[(size_t)grow * NCLS + n * 16 + fr] = v[n] - m - ls;
    }
  }
}

extern "C" void kernel_launch(void* const* d_in, const int* in_sizes, int n_in,
                              void* d_out, int out_size, void* d_ws, size_t ws_size,
                              hipStream_t stream) {
  const float* x = (const float*)d_in[0];
  const int* src = (const int*)d_in[1];
  const int* dst = (const int*)d_in[2];
  const float* W1 = (const float*)d_in[3];
  const float* b1 = (const float*)d_in[4];
  const float* W2 = (const float*)d_in[5];
  const float* b2 = (const float*)d_in[6];
  const float* Wf = (const float*)d_in[7];
  const float* bf = (const float*)d_in[8];
  float* out = (float*)d_out;

  // ---- workspace layout (~78 MB), 256B-aligned blocks ----
  char* base = (char*)d_ws;
  size_t off = 0;
  auto alloc = [&](size_t bytes) -> void* {
    off = (off + 255) & ~(size_t)255;
    void* p = base + off;
    off += bytes;
    return p;
  };
  // cs and cnt as ONE contiguous block so a single memset covers both
  unsigned* cs = (unsigned*)alloc(2 * (size_t)N_NODES * 4);
  unsigned* cnt = cs + N_NODES;
  int* bucket = (int*)alloc((size_t)N_NODES * CAP * 4);                   // 25.6 MB
  unsigned short* P1 = (unsigned short*)alloc((size_t)N_NODES * F1 * 2);  // h1, then h2
  unsigned short* P2 = (unsigned short*)alloc((size_t)N_NODES * F1 * 2);  // h1f, then agg2
  unsigned short* wt1 = (unsigned short*)alloc((size_t)F1 * F0 * 2);
  unsigned short* wt2 = (unsigned short*)alloc((size_t)F2 * F1 * 2);
  unsigned short* wtf = (unsigned short*)alloc((size_t)NFPAD * F2 * 2);

  unsigned short* h1 = P1;
  unsigned short* h1f = P2;
  unsigned short* h2 = P1;             // aliases h1 (dead after gather128)
  unsigned short* agg2 = P2;           // aliases h1f (dead after gemm2)

  hipMemsetAsync(cs, 0, 2 * (size_t)N_NODES * sizeof(unsigned), stream);

  // one merged cast kernel (wt1 + wt2 + wtf)
  constexpr int CAST_TOTAL = F1 * F0 + F2 * F1 + NFPAD * F2;  // 54272
  k_castall<<<(CAST_TOTAL + 255) / 256, 256, 0, stream>>>(W1, W2, Wf, wt1, wt2, wtf);

  // fused: bucket-fill + layer-1 GEMM (no cross-dependency; roles interleaved)
  constexpr int NB_GEMM = (N_NODES + 127) / 128;
  constexpr int NB_FILL = 2048;
  k_fill_gemm1<<<NB_GEMM + NB_FILL, 256, 0, stream>>>(src, dst, cs, cnt, bucket, x, wt1, h1);

  // layer 1 aggregate (dsrc/ddst computed inline from cs/cnt)
  k_gather128<<<(N_NODES + 3) / 4, 256, 0, stream>>>(bucket, cs, cnt, h1, b1, h1f);

  // layer 2 GEMM (BM=64 -> 1563 blocks for TLP)
  k_gemm2<<<(N_NODES + 63) / 64, 128, 0, stream>>>(h1f, wt2, cs, h2);

  // layer 2 aggregate
  k_gather64<<<(N_NODES + 3) / 4, 256, 0, stream>>>(bucket, cnt, h2, b2, agg2);

  // classifier + log_softmax (MFMA, in-register softmax)
  k_final_mfma<<<(N_NODES + 63) / 64, 256, 0, stream>>>(agg2, wtf, bf, out);
}